// Round 7
// baseline (300.704 us; speedup 1.0000x reference)
//
#include <hip/hip_runtime.h>
#include <hip/hip_fp16.h>

#define N_NODES 100000
#define DUMMY   N_NODES
#define DIM     128
#define N_EDGES 1600000
#define N_PRED  500000
#define ROWS    48                                   // slot-table row capacity (max deg ~35)
#define NH2     (N_NODES * 64)                       // 6.4M half2/float2 elements
#define CPY_NB  1024                                 // blocks for streaming copy work
#define CPY_STRIDE (CPY_NB * 256)

#define NBINS   391                                  // bin = dst >> 8 (256 nodes/bin)
#define BINCAP  5120                                 // mean 4092, std 64 -> 16 sigma headroom
#define BIN_NB  391                                  // 391*256 threads * 16 edges = 1.6M
#define MAXQ    (BINCAP / 256)                       // 20 edges/thread in csr phase

#define AGG_NB    2048                               // persistent grid: 8 blocks/CU
#define AGG_WAVES (AGG_NB * 4)                       // 8192 waves, ~12 nodes each
#define DOT_NB    2048
#define DOT_WAVES (DOT_NB * 4)
#define NPGRP     (N_PRED / 8)                       // 62500 8-pair groups

// ---------------- prep: bincur init + dummy zero-rows ----------------

__global__ __launch_bounds__(256) void prep_kernel(int* __restrict__ bincur,
                                                   __half2* __restrict__ gA,
                                                   __half2* __restrict__ gB,
                                                   __half2* __restrict__ e16,
                                                   float* __restrict__ dinv) {
    int i = blockIdx.x * blockDim.x + threadIdx.x;
    if (i < NBINS) bincur[i] = i * BINCAP;
    if (i < 192) {
        __half2 z = __float22half2_rn(make_float2(0.f, 0.f));
        if (i < 64)       gA[(size_t)DUMMY * 64 + i] = z;
        else if (i < 128) gB[(size_t)DUMMY * 64 + (i - 64)] = z;
        else              e16[(size_t)DUMMY * 64 + (i - 128)] = z;
    }
    if (i == 192) dinv[DUMMY] = 0.0f;
}

// ---------------- phase 1: bin edges (LDS hist + rank, 1 global atomic per block,bin) | e16 copy ----
// packed entry: (local_d << 17) | src,  local_d = dst & 255 (8b), src < 2^17.

__global__ __launch_bounds__(256) void bin_or_copy_kernel(const int* __restrict__ src,
                                                          const int* __restrict__ dst,
                                                          const float* __restrict__ emb,
                                                          int* __restrict__ bincur,
                                                          int* __restrict__ binbuf,
                                                          __half2* __restrict__ e16) {
    int b = blockIdx.x;
    if (b < BIN_NB) {
        __shared__ int hist[NBINS];
        __shared__ int base[NBINS];
        int t = b * 256 + threadIdx.x;
        int e0 = t * 16;
        bool active = (e0 < N_EDGES);   // 1.6M/16 = 100000 threads exactly; no partial tail
        for (int i = threadIdx.x; i < NBINS; i += 256) hist[i] = 0;
        __syncthreads();
        int dd[16], ss[16], lr[16];
        if (active) {
            #pragma unroll
            for (int q = 0; q < 4; ++q) {
                int4 d4 = *(const int4*)&dst[e0 + q * 4];
                int4 s4 = *(const int4*)&src[e0 + q * 4];
                dd[q * 4 + 0] = d4.x; dd[q * 4 + 1] = d4.y; dd[q * 4 + 2] = d4.z; dd[q * 4 + 3] = d4.w;
                ss[q * 4 + 0] = s4.x; ss[q * 4 + 1] = s4.y; ss[q * 4 + 2] = s4.z; ss[q * 4 + 3] = s4.w;
            }
            #pragma unroll
            for (int j = 0; j < 16; ++j) lr[j] = atomicAdd(&hist[dd[j] >> 8], 1);
        }
        __syncthreads();
        // reserve global space: one scattered global atomic per (block, nonempty bin)
        for (int i = threadIdx.x; i < NBINS; i += 256) {
            int h = hist[i];
            base[i] = h ? atomicAdd(&bincur[i], h) : 0;
        }
        __syncthreads();
        if (active) {
            #pragma unroll
            for (int j = 0; j < 16; ++j) {
                int bin = dd[j] >> 8;
                int pos = base[bin] + lr[j];
                if (pos < (bin + 1) * BINCAP)           // capacity guard (never trips)
                    binbuf[pos] = ((dd[j] & 255) << 17) | ss[j];
            }
        }
    } else {
        // ---- streaming emb -> fp16 copy (grid-stride over 1024 blocks) ----
        const float2* em2 = (const float2*)emb;
        int idx = (b - BIN_NB) * 256 + threadIdx.x;
        for (; idx < NH2; idx += CPY_STRIDE)
            e16[idx] = __float22half2_rn(em2[idx]);
    }
}

// ---------------- phase 2: per-bin CSR finalize + pad16 — zero global atomics ----------------
// rank via LDS atomics on 256 per-node counters; deg/dinv from the LDS histogram;
// rows padded to x16 with DUMMY so agg can do maskless 16-edge batches.

__global__ __launch_bounds__(256) void csr_kernel(const int* __restrict__ bincur,
                                                  const int* __restrict__ binbuf,
                                                  int* __restrict__ deg,
                                                  float* __restrict__ dinv,
                                                  int* __restrict__ colp) {
    int b = blockIdx.x;
    __shared__ int cl[256];
    cl[threadIdx.x] = 0;
    __syncthreads();
    int start = b * BINCAP;
    int cnt = bincur[b] - start;
    if (cnt > BINCAP) cnt = BINCAP;
    int pq[MAXQ], rq[MAXQ];
    #pragma unroll
    for (int q = 0; q < MAXQ; ++q) {
        int i = threadIdx.x + q * 256;
        if (i < cnt) {
            int p = binbuf[start + i];
            pq[q] = p;
            rq[q] = atomicAdd(&cl[p >> 17], 1);
        } else {
            pq[q] = -1;
            rq[q] = ROWS;
        }
    }
    __syncthreads();
    int n = (b << 8) + threadIdx.x;
    if (n < N_NODES) {
        int d = cl[threadIdx.x];
        int dcl = (d > ROWS) ? ROWS : d;
        deg[n] = dcl;
        dinv[n] = (d > 0) ? (float)(1.0 / sqrt((double)d)) : 0.0f;
        int pe = (dcl + 15) & ~15;            // pad row to x16 with DUMMY (maskless agg)
        for (int r = dcl; r < pe; ++r) colp[n * ROWS + r] = DUMMY;
    }
    // scatter real entries (disjoint slots [0, dcl) per node, order-independent)
    #pragma unroll
    for (int q = 0; q < MAXQ; ++q) {
        if (pq[q] >= 0 && rq[q] < ROWS) {
            int ld = pq[q] >> 17;
            colp[(size_t)((b << 8) + ld) * ROWS + rq[q]] = pq[q] & 0x1FFFF;
        }
    }
}

// ---------------- agg layer 1: persistent waves, maskless 16-batches, in-loop dinv[s] ----------------
// z = e16[n] + dinv[n] * sum_s dinv[s]*e16[s] ; out = h2(dinv[n]*z)   [mid layer]
// DUMMY slots contribute exactly 0 (dinv[DUMMY]=0, e16 dummy row = 0).

__global__ __launch_bounds__(256) void agg1_kernel(const __half2* __restrict__ e16,
                                                   const float* __restrict__ dinv,
                                                   const int* __restrict__ deg,
                                                   const int* __restrict__ colp,
                                                   __half2* __restrict__ g_out) {
    int wav = (blockIdx.x * 256 + threadIdx.x) >> 6;
    unsigned lane = threadIdx.x & 63;
    for (int n = wav; n < N_NODES; n += AGG_WAVES) {
        int d = deg[n];
        int nb = (d + 15) >> 4;                   // 0..3 maskless 16-edge batches
        const int4* cp = (const int4*)(colp + (size_t)n * ROWS);
        float ax0 = 0.f, ay0 = 0.f, ax1 = 0.f, ay1 = 0.f;
        float ax2 = 0.f, ay2 = 0.f, ax3 = 0.f, ay3 = 0.f;
        for (int t = 0; t < nb; ++t) {
            int4 c0 = cp[t * 4 + 0];
            int4 c1 = cp[t * 4 + 1];
            int4 c2 = cp[t * 4 + 2];
            int4 c3 = cp[t * 4 + 3];
            float w0  = dinv[c0.x], w1  = dinv[c0.y], w2  = dinv[c0.z], w3  = dinv[c0.w];
            float w4  = dinv[c1.x], w5  = dinv[c1.y], w6  = dinv[c1.z], w7  = dinv[c1.w];
            float w8  = dinv[c2.x], w9  = dinv[c2.y], w10 = dinv[c2.z], w11 = dinv[c2.w];
            float w12 = dinv[c3.x], w13 = dinv[c3.y], w14 = dinv[c3.z], w15 = dinv[c3.w];
            __half2 h0  = e16[((unsigned)c0.x << 6) | lane];
            __half2 h1  = e16[((unsigned)c0.y << 6) | lane];
            __half2 h2  = e16[((unsigned)c0.z << 6) | lane];
            __half2 h3  = e16[((unsigned)c0.w << 6) | lane];
            __half2 h4  = e16[((unsigned)c1.x << 6) | lane];
            __half2 h5  = e16[((unsigned)c1.y << 6) | lane];
            __half2 h6  = e16[((unsigned)c1.z << 6) | lane];
            __half2 h7  = e16[((unsigned)c1.w << 6) | lane];
            __half2 h8  = e16[((unsigned)c2.x << 6) | lane];
            __half2 h9  = e16[((unsigned)c2.y << 6) | lane];
            __half2 h10 = e16[((unsigned)c2.z << 6) | lane];
            __half2 h11 = e16[((unsigned)c2.w << 6) | lane];
            __half2 h12 = e16[((unsigned)c3.x << 6) | lane];
            __half2 h13 = e16[((unsigned)c3.y << 6) | lane];
            __half2 h14 = e16[((unsigned)c3.z << 6) | lane];
            __half2 h15 = e16[((unsigned)c3.w << 6) | lane];
            float2 f;
            f = __half22float2(h0);  ax0 += w0  * f.x; ay0 += w0  * f.y;
            f = __half22float2(h1);  ax1 += w1  * f.x; ay1 += w1  * f.y;
            f = __half22float2(h2);  ax2 += w2  * f.x; ay2 += w2  * f.y;
            f = __half22float2(h3);  ax3 += w3  * f.x; ay3 += w3  * f.y;
            f = __half22float2(h4);  ax0 += w4  * f.x; ay0 += w4  * f.y;
            f = __half22float2(h5);  ax1 += w5  * f.x; ay1 += w5  * f.y;
            f = __half22float2(h6);  ax2 += w6  * f.x; ay2 += w6  * f.y;
            f = __half22float2(h7);  ax3 += w7  * f.x; ay3 += w7  * f.y;
            f = __half22float2(h8);  ax0 += w8  * f.x; ay0 += w8  * f.y;
            f = __half22float2(h9);  ax1 += w9  * f.x; ay1 += w9  * f.y;
            f = __half22float2(h10); ax2 += w10 * f.x; ay2 += w10 * f.y;
            f = __half22float2(h11); ax3 += w11 * f.x; ay3 += w11 * f.y;
            f = __half22float2(h12); ax0 += w12 * f.x; ay0 += w12 * f.y;
            f = __half22float2(h13); ax1 += w13 * f.x; ay1 += w13 * f.y;
            f = __half22float2(h14); ax2 += w14 * f.x; ay2 += w14 * f.y;
            f = __half22float2(h15); ax3 += w15 * f.x; ay3 += w15 * f.y;
        }
        float sx = (ax0 + ax1) + (ax2 + ax3);
        float sy = (ay0 + ay1) + (ay2 + ay3);
        float dv = dinv[n];
        unsigned idx = ((unsigned)n << 6) | lane;
        float2 e = __half22float2(e16[idx]);
        float zx = (e.x + dv * sx) * dv, zy = (e.y + dv * sy) * dv;   // mid layer
        g_out[idx] = __float22half2_rn(make_float2(zx, zy));
    }
}

// ---------------- agg layers 2/3: persistent waves, maskless 16-batches ----------------
// z = e16[n] + dinv[n] * sum g_in[col] ; mid: out = h2(dinv*z) ; last: out = h2(z)

__global__ __launch_bounds__(256) void agg_kernel(const __half2* __restrict__ g_in,
                                                  const __half2* __restrict__ e16,
                                                  const float* __restrict__ dinv,
                                                  const int* __restrict__ deg,
                                                  const int* __restrict__ colp,
                                                  __half2* __restrict__ g_out,
                                                  int last) {
    int wav = (blockIdx.x * 256 + threadIdx.x) >> 6;
    unsigned lane = threadIdx.x & 63;
    for (int n = wav; n < N_NODES; n += AGG_WAVES) {
        int d = deg[n];
        int nb = (d + 15) >> 4;                   // 0..3 maskless 16-edge batches
        const int4* cp = (const int4*)(colp + (size_t)n * ROWS);
        float ax0 = 0.f, ay0 = 0.f, ax1 = 0.f, ay1 = 0.f;
        float ax2 = 0.f, ay2 = 0.f, ax3 = 0.f, ay3 = 0.f;
        for (int t = 0; t < nb; ++t) {
            int4 c0 = cp[t * 4 + 0];
            int4 c1 = cp[t * 4 + 1];
            int4 c2 = cp[t * 4 + 2];
            int4 c3 = cp[t * 4 + 3];
            __half2 h0  = g_in[((unsigned)c0.x << 6) | lane];
            __half2 h1  = g_in[((unsigned)c0.y << 6) | lane];
            __half2 h2  = g_in[((unsigned)c0.z << 6) | lane];
            __half2 h3  = g_in[((unsigned)c0.w << 6) | lane];
            __half2 h4  = g_in[((unsigned)c1.x << 6) | lane];
            __half2 h5  = g_in[((unsigned)c1.y << 6) | lane];
            __half2 h6  = g_in[((unsigned)c1.z << 6) | lane];
            __half2 h7  = g_in[((unsigned)c1.w << 6) | lane];
            __half2 h8  = g_in[((unsigned)c2.x << 6) | lane];
            __half2 h9  = g_in[((unsigned)c2.y << 6) | lane];
            __half2 h10 = g_in[((unsigned)c2.z << 6) | lane];
            __half2 h11 = g_in[((unsigned)c2.w << 6) | lane];
            __half2 h12 = g_in[((unsigned)c3.x << 6) | lane];
            __half2 h13 = g_in[((unsigned)c3.y << 6) | lane];
            __half2 h14 = g_in[((unsigned)c3.z << 6) | lane];
            __half2 h15 = g_in[((unsigned)c3.w << 6) | lane];
            float2 f;
            f = __half22float2(h0);  ax0 += f.x; ay0 += f.y;
            f = __half22float2(h1);  ax1 += f.x; ay1 += f.y;
            f = __half22float2(h2);  ax2 += f.x; ay2 += f.y;
            f = __half22float2(h3);  ax3 += f.x; ay3 += f.y;
            f = __half22float2(h4);  ax0 += f.x; ay0 += f.y;
            f = __half22float2(h5);  ax1 += f.x; ay1 += f.y;
            f = __half22float2(h6);  ax2 += f.x; ay2 += f.y;
            f = __half22float2(h7);  ax3 += f.x; ay3 += f.y;
            f = __half22float2(h8);  ax0 += f.x; ay0 += f.y;
            f = __half22float2(h9);  ax1 += f.x; ay1 += f.y;
            f = __half22float2(h10); ax2 += f.x; ay2 += f.y;
            f = __half22float2(h11); ax3 += f.x; ay3 += f.y;
            f = __half22float2(h12); ax0 += f.x; ay0 += f.y;
            f = __half22float2(h13); ax1 += f.x; ay1 += f.y;
            f = __half22float2(h14); ax2 += f.x; ay2 += f.y;
            f = __half22float2(h15); ax3 += f.x; ay3 += f.y;
        }
        float sx = (ax0 + ax1) + (ax2 + ax3);
        float sy = (ay0 + ay1) + (ay2 + ay3);
        float dv = dinv[n];
        unsigned idx = ((unsigned)n << 6) | lane;
        float2 e = __half22float2(e16[idx]);
        float zx = e.x + dv * sx, zy = e.y + dv * sy;
        if (!last) { zx *= dv; zy *= dv; }
        g_out[idx] = __float22half2_rn(make_float2(zx, zy));
    }
}

// persistent waves: 8 pairs/wave-iteration, 8 lanes/pair; fp16 z3 rows (256B)
__global__ __launch_bounds__(256) void dot_kernel(const int* __restrict__ pa,
                                                  const int* __restrict__ pb,
                                                  const float4* __restrict__ z16,
                                                  float* __restrict__ out) {
    int wav = (blockIdx.x * 256 + threadIdx.x) >> 6;
    int lane = threadIdx.x & 63;
    int slot = lane >> 3;
    int gl = lane & 7;
    for (int wid = wav; wid < NPGRP; wid += DOT_WAVES) {
        int p = wid * 8 + slot;
        int a = pa[p], b = pb[p];
        float4 qa0 = z16[(size_t)a * 16 + gl * 2];
        float4 qa1 = z16[(size_t)a * 16 + gl * 2 + 1];
        float4 qb0 = z16[(size_t)b * 16 + gl * 2];
        float4 qb1 = z16[(size_t)b * 16 + gl * 2 + 1];
        const __half2* ha0 = (const __half2*)&qa0;
        const __half2* ha1 = (const __half2*)&qa1;
        const __half2* hb0 = (const __half2*)&qb0;
        const __half2* hb1 = (const __half2*)&qb1;
        float d = 0.f;
        #pragma unroll
        for (int i = 0; i < 4; ++i) {
            float2 fa0 = __half22float2(ha0[i]);
            float2 fb0 = __half22float2(hb0[i]);
            float2 fa1 = __half22float2(ha1[i]);
            float2 fb1 = __half22float2(hb1[i]);
            d += fa0.x * fb0.x + fa0.y * fb0.y;
            d += fa1.x * fb1.x + fa1.y * fb1.y;
        }
        d += __shfl_xor(d, 1, 64);
        d += __shfl_xor(d, 2, 64);
        d += __shfl_xor(d, 4, 64);
        if (gl == 0) out[p] = d * 0.0625f;
    }
}

// ---------------- launcher ----------------

extern "C" void kernel_launch(void* const* d_in, const int* in_sizes, int n_in,
                              void* d_out, int out_size, void* d_ws, size_t ws_size,
                              hipStream_t stream) {
    const int*   edge_index = (const int*)d_in[0];
    const int*   src  = edge_index;
    const int*   dst  = edge_index + N_EDGES;
    const int*   eli  = (const int*)d_in[1];
    const int*   pa   = eli;
    const int*   pb   = eli + N_PRED;
    const float* emb  = (const float*)d_in[2];
    float*       out  = (float*)d_out;

    char* wsp = (char*)d_ws;
    auto alloc = [&](size_t bytes) -> void* {
        void* p = (void*)wsp;
        wsp += (bytes + 255) & ~(size_t)255;
        return p;
    };
    float*   dinv   = (float*)  alloc((size_t)(N_NODES + 1) * 4);
    int*     deg    = (int*)    alloc((size_t)N_NODES * 4);
    int*     bincur = (int*)    alloc((size_t)NBINS * 4);
    int*     colp   = (int*)    alloc(((size_t)N_NODES * ROWS + 256) * 4);  // 19.2 MB + pad
    __half2* gA     = (__half2*)alloc((size_t)(N_NODES + 1) * 64 * 4);
    __half2* gB     = (__half2*)alloc((size_t)(N_NODES + 1) * 64 * 4);
    __half2* e16    = (__half2*)alloc((size_t)(N_NODES + 1) * 64 * 4);
    // binbuf (8 MB) lifetime-overlaid on gA (first written by agg1, after csr)
    int*     binbuf = (int*)gA;

    const int tb = 256;
    prep_kernel<<<2, tb, 0, stream>>>(bincur, gA, gB, e16, dinv);
    // phase 1: bin+rank via LDS atomics, 153K global reserve atomics | e16 fp16 copy
    bin_or_copy_kernel<<<BIN_NB + CPY_NB, tb, 0, stream>>>(src, dst, emb, bincur, binbuf, e16);
    // phase 2: per-bin CSR finalize + pad16 (zero global atomics), deg + dinv fused
    csr_kernel<<<NBINS, tb, 0, stream>>>(bincur, binbuf, deg, dinv, colp);

    // 3 Horner layers on persistent 2048-block grids (8 blocks/CU, ~12 nodes/wave)
    agg1_kernel<<<AGG_NB, tb, 0, stream>>>(e16, dinv, deg, colp, gA);              // gA = h2(dv*z1)
    agg_kernel<<<AGG_NB, tb, 0, stream>>>(gA, e16, dinv, deg, colp, gB, 0);        // gB = h2(dv*z2)
    agg_kernel<<<AGG_NB, tb, 0, stream>>>(gB, e16, dinv, deg, colp, gA, 1);        // gA = h2(z3)

    // link-prediction dots on fp16 z3 (persistent 2048-block grid)
    dot_kernel<<<DOT_NB, tb, 0, stream>>>(pa, pb, (const float4*)gA, out);
}

// Round 8
// 271.834 us; speedup vs baseline: 1.1062x; 1.1062x over previous
//
#include <hip/hip_runtime.h>
#include <hip/hip_fp16.h>

#define N_NODES 100000
#define DUMMY   N_NODES
#define DIM     128
#define N_EDGES 1600000
#define N_PRED  500000
#define ROWS    48                                   // slot-table row capacity (max deg ~35)
#define NH2     (N_NODES * 64)                       // 6.4M half2/float2 elements
#define CPY_NB  1024                                 // blocks for streaming copy work
#define CPY_STRIDE (CPY_NB * 256)

#define NBINS   391                                  // bin = dst >> 8 (256 nodes/bin)
#define BINCAP  5120                                 // mean 4092, std 64 -> 16 sigma headroom
#define BIN_NB  391                                  // 391*256 threads * 16 edges = 1.6M
#define MAXQ    (BINCAP / 256)                       // 20 edges/thread in csr phase

// ---------------- prep: bincur init + dummy zero-rows ----------------

__global__ __launch_bounds__(256) void prep_kernel(int* __restrict__ bincur,
                                                   __half2* __restrict__ gA,
                                                   __half2* __restrict__ gB,
                                                   __half2* __restrict__ e16,
                                                   float* __restrict__ dinv) {
    int i = blockIdx.x * blockDim.x + threadIdx.x;
    if (i < NBINS) bincur[i] = i * BINCAP;
    if (i < 192) {
        __half2 z = __float22half2_rn(make_float2(0.f, 0.f));
        if (i < 64)       gA[(size_t)DUMMY * 64 + i] = z;
        else if (i < 128) gB[(size_t)DUMMY * 64 + (i - 64)] = z;
        else              e16[(size_t)DUMMY * 64 + (i - 128)] = z;
    }
    if (i == 192) dinv[DUMMY] = 0.0f;
}

// ---------------- phase 1: bin edges (LDS hist + rank, 1 global atomic per block,bin) | e16 copy ----
// packed entry: (local_d << 17) | src,  local_d = dst & 255 (8b), src < 2^17.

__global__ __launch_bounds__(256) void bin_or_copy_kernel(const int* __restrict__ src,
                                                          const int* __restrict__ dst,
                                                          const float* __restrict__ emb,
                                                          int* __restrict__ bincur,
                                                          int* __restrict__ binbuf,
                                                          __half2* __restrict__ e16) {
    int b = blockIdx.x;
    if (b < BIN_NB) {
        __shared__ int hist[NBINS];
        __shared__ int base[NBINS];
        int t = b * 256 + threadIdx.x;
        int e0 = t * 16;
        bool active = (e0 < N_EDGES);   // 1.6M/16 = 100000 threads exactly; no partial tail
        for (int i = threadIdx.x; i < NBINS; i += 256) hist[i] = 0;
        __syncthreads();
        int dd[16], ss[16], lr[16];
        if (active) {
            #pragma unroll
            for (int q = 0; q < 4; ++q) {
                int4 d4 = *(const int4*)&dst[e0 + q * 4];
                int4 s4 = *(const int4*)&src[e0 + q * 4];
                dd[q * 4 + 0] = d4.x; dd[q * 4 + 1] = d4.y; dd[q * 4 + 2] = d4.z; dd[q * 4 + 3] = d4.w;
                ss[q * 4 + 0] = s4.x; ss[q * 4 + 1] = s4.y; ss[q * 4 + 2] = s4.z; ss[q * 4 + 3] = s4.w;
            }
            #pragma unroll
            for (int j = 0; j < 16; ++j) lr[j] = atomicAdd(&hist[dd[j] >> 8], 1);
        }
        __syncthreads();
        // reserve global space: one scattered global atomic per (block, nonempty bin)
        for (int i = threadIdx.x; i < NBINS; i += 256) {
            int h = hist[i];
            base[i] = h ? atomicAdd(&bincur[i], h) : 0;
        }
        __syncthreads();
        if (active) {
            #pragma unroll
            for (int j = 0; j < 16; ++j) {
                int bin = dd[j] >> 8;
                int pos = base[bin] + lr[j];
                if (pos < (bin + 1) * BINCAP)           // capacity guard (never trips)
                    binbuf[pos] = ((dd[j] & 255) << 17) | ss[j];
            }
        }
    } else {
        // ---- streaming emb -> fp16 copy (grid-stride over 1024 blocks) ----
        const float2* em2 = (const float2*)emb;
        int idx = (b - BIN_NB) * 256 + threadIdx.x;
        for (; idx < NH2; idx += CPY_STRIDE)
            e16[idx] = __float22half2_rn(em2[idx]);
    }
}

// ---------------- phase 2: per-bin CSR finalize + pad16 — zero global atomics ----------------
// rank via LDS atomics on 256 per-node counters; deg/dinv from the LDS histogram;
// rows padded to x16 with DUMMY so agg can do maskless 16-edge batches.

__global__ __launch_bounds__(256) void csr_kernel(const int* __restrict__ bincur,
                                                  const int* __restrict__ binbuf,
                                                  int* __restrict__ deg,
                                                  float* __restrict__ dinv,
                                                  int* __restrict__ colp) {
    int b = blockIdx.x;
    __shared__ int cl[256];
    cl[threadIdx.x] = 0;
    __syncthreads();
    int start = b * BINCAP;
    int cnt = bincur[b] - start;
    if (cnt > BINCAP) cnt = BINCAP;
    int pq[MAXQ], rq[MAXQ];
    #pragma unroll
    for (int q = 0; q < MAXQ; ++q) {
        int i = threadIdx.x + q * 256;
        if (i < cnt) {
            int p = binbuf[start + i];
            pq[q] = p;
            rq[q] = atomicAdd(&cl[p >> 17], 1);
        } else {
            pq[q] = -1;
            rq[q] = ROWS;
        }
    }
    __syncthreads();
    int n = (b << 8) + threadIdx.x;
    if (n < N_NODES) {
        int d = cl[threadIdx.x];
        int dcl = (d > ROWS) ? ROWS : d;
        deg[n] = dcl;
        dinv[n] = (d > 0) ? (float)(1.0 / sqrt((double)d)) : 0.0f;
        int pe = (dcl + 15) & ~15;            // pad row to x16 with DUMMY (maskless agg)
        for (int r = dcl; r < pe; ++r) colp[n * ROWS + r] = DUMMY;
    }
    // scatter real entries (disjoint slots [0, dcl) per node, order-independent)
    #pragma unroll
    for (int q = 0; q < MAXQ; ++q) {
        if (pq[q] >= 0 && rq[q] < ROWS) {
            int ld = pq[q] >> 17;
            colp[(size_t)((b << 8) + ld) * ROWS + rq[q]] = pq[q] & 0x1FFFF;
        }
    }
}

// ---------------- agg: wide-gather layout ----------------
// lane-group grp=lane>>4 picks the edge, sub=lane&15 picks the 16B slice:
// ONE dwordx4 VMEM instruction fetches 4 full 256B rows (vs 4B/lane = 1 row).
// Each lane accumulates its 8 dims; node ends with xor16/xor32 shfl fold.

__device__ __forceinline__ int pick(int4 c, unsigned g) {
    int e = c.x;
    e = (g == 1) ? c.y : e;
    e = (g == 2) ? c.z : e;
    e = (g == 3) ? c.w : e;
    return e;
}

__device__ __forceinline__ void acc8w(float* a, float4 q, float w) {
    const __half2* h = (const __half2*)&q;
    #pragma unroll
    for (int j = 0; j < 4; ++j) {
        float2 f = __half22float2(h[j]);
        a[2 * j]     += w * f.x;
        a[2 * j + 1] += w * f.y;
    }
}

__device__ __forceinline__ void acc8(float* a, float4 q) {
    const __half2* h = (const __half2*)&q;
    #pragma unroll
    for (int j = 0; j < 4; ++j) {
        float2 f = __half22float2(h[j]);
        a[2 * j]     += f.x;
        a[2 * j + 1] += f.y;
    }
}

// layer 1: z = e16[n] + dinv[n] * sum_s dinv[s]*e16[s] ; out = h2(dinv[n]*z)  [mid]
__global__ __launch_bounds__(256) void agg1_kernel(const __half2* __restrict__ e16,
                                                   const float* __restrict__ dinv,
                                                   const int* __restrict__ deg,
                                                   const int* __restrict__ colp,
                                                   __half2* __restrict__ g_out) {
    int n = (blockIdx.x * 256 + threadIdx.x) >> 6;
    unsigned lane = threadIdx.x & 63;
    if (n >= N_NODES) return;
    unsigned grp = lane >> 4, sub = lane & 15;
    int d = deg[n];
    int nb = (d + 15) >> 4;
    const int4* cp = (const int4*)(colp + (size_t)n * ROWS);
    const float4* e4 = (const float4*)e16;
    float acc[8] = {0.f, 0.f, 0.f, 0.f, 0.f, 0.f, 0.f, 0.f};
    for (int t = 0; t < nb; ++t) {
        int4 c0 = cp[t * 4 + 0];
        int4 c1 = cp[t * 4 + 1];
        int4 c2 = cp[t * 4 + 2];
        int4 c3 = cp[t * 4 + 3];
        int ea = pick(c0, grp), eb = pick(c1, grp), ec = pick(c2, grp), ed = pick(c3, grp);
        float wa = dinv[ea], wb = dinv[eb], wc = dinv[ec], wd = dinv[ed];
        float4 qa = e4[((unsigned)ea << 4) | sub];
        float4 qb = e4[((unsigned)eb << 4) | sub];
        float4 qc = e4[((unsigned)ec << 4) | sub];
        float4 qd = e4[((unsigned)ed << 4) | sub];
        acc8w(acc, qa, wa);
        acc8w(acc, qb, wb);
        acc8w(acc, qc, wc);
        acc8w(acc, qd, wd);
    }
    #pragma unroll
    for (int k = 0; k < 8; ++k) {
        acc[k] += __shfl_xor(acc[k], 16, 64);
        acc[k] += __shfl_xor(acc[k], 32, 64);
    }
    float dv = dinv[n];
    float4 ev = e4[((unsigned)n << 4) | sub];
    const __half2* eh = (const __half2*)&ev;
    float4 res;
    __half2* rh = (__half2*)&res;
    #pragma unroll
    for (int j = 0; j < 4; ++j) {
        float2 f = __half22float2(eh[j]);
        float zx = (f.x + dv * acc[2 * j]) * dv;       // mid layer
        float zy = (f.y + dv * acc[2 * j + 1]) * dv;
        rh[j] = __float22half2_rn(make_float2(zx, zy));
    }
    if (grp == 0) ((float4*)g_out)[((unsigned)n << 4) | sub] = res;
}

// layers 2/3: z = e16[n] + dinv[n] * sum g_in[col] ; mid: h2(dinv*z) ; last: h2(z)
__global__ __launch_bounds__(256) void agg_kernel(const __half2* __restrict__ g_in,
                                                  const __half2* __restrict__ e16,
                                                  const float* __restrict__ dinv,
                                                  const int* __restrict__ deg,
                                                  const int* __restrict__ colp,
                                                  __half2* __restrict__ g_out,
                                                  int last) {
    int n = (blockIdx.x * 256 + threadIdx.x) >> 6;
    unsigned lane = threadIdx.x & 63;
    if (n >= N_NODES) return;
    unsigned grp = lane >> 4, sub = lane & 15;
    int d = deg[n];
    int nb = (d + 15) >> 4;
    const int4* cp = (const int4*)(colp + (size_t)n * ROWS);
    const float4* g4 = (const float4*)g_in;
    float acc[8] = {0.f, 0.f, 0.f, 0.f, 0.f, 0.f, 0.f, 0.f};
    for (int t = 0; t < nb; ++t) {
        int4 c0 = cp[t * 4 + 0];
        int4 c1 = cp[t * 4 + 1];
        int4 c2 = cp[t * 4 + 2];
        int4 c3 = cp[t * 4 + 3];
        int ea = pick(c0, grp), eb = pick(c1, grp), ec = pick(c2, grp), ed = pick(c3, grp);
        float4 qa = g4[((unsigned)ea << 4) | sub];
        float4 qb = g4[((unsigned)eb << 4) | sub];
        float4 qc = g4[((unsigned)ec << 4) | sub];
        float4 qd = g4[((unsigned)ed << 4) | sub];
        acc8(acc, qa);
        acc8(acc, qb);
        acc8(acc, qc);
        acc8(acc, qd);
    }
    #pragma unroll
    for (int k = 0; k < 8; ++k) {
        acc[k] += __shfl_xor(acc[k], 16, 64);
        acc[k] += __shfl_xor(acc[k], 32, 64);
    }
    float dv = dinv[n];
    float4 ev = ((const float4*)e16)[((unsigned)n << 4) | sub];
    const __half2* eh = (const __half2*)&ev;
    float4 res;
    __half2* rh = (__half2*)&res;
    #pragma unroll
    for (int j = 0; j < 4; ++j) {
        float2 f = __half22float2(eh[j]);
        float zx = f.x + dv * acc[2 * j];
        float zy = f.y + dv * acc[2 * j + 1];
        if (!last) { zx *= dv; zy *= dv; }
        rh[j] = __float22half2_rn(make_float2(zx, zy));
    }
    if (grp == 0) ((float4*)g_out)[((unsigned)n << 4) | sub] = res;
}

// 8 pairs/wave, 8 lanes/pair; fp16 z3 rows (256B), 2x float4(=8 half2) per side per lane
__global__ __launch_bounds__(256) void dot_kernel(const int* __restrict__ pa,
                                                  const int* __restrict__ pb,
                                                  const float4* __restrict__ z16,
                                                  float* __restrict__ out) {
    int wid = (blockIdx.x * blockDim.x + threadIdx.x) >> 6;
    int lane = threadIdx.x & 63;
    int slot = lane >> 3;
    int gl = lane & 7;
    int p = wid * 8 + slot;      // exact: 15625 blocks * 32 pairs = 500000
    int a = pa[p], b = pb[p];
    float4 qa0 = z16[(size_t)a * 16 + gl * 2];
    float4 qa1 = z16[(size_t)a * 16 + gl * 2 + 1];
    float4 qb0 = z16[(size_t)b * 16 + gl * 2];
    float4 qb1 = z16[(size_t)b * 16 + gl * 2 + 1];
    const __half2* ha0 = (const __half2*)&qa0;
    const __half2* ha1 = (const __half2*)&qa1;
    const __half2* hb0 = (const __half2*)&qb0;
    const __half2* hb1 = (const __half2*)&qb1;
    float d = 0.f;
    #pragma unroll
    for (int i = 0; i < 4; ++i) {
        float2 fa0 = __half22float2(ha0[i]);
        float2 fb0 = __half22float2(hb0[i]);
        float2 fa1 = __half22float2(ha1[i]);
        float2 fb1 = __half22float2(hb1[i]);
        d += fa0.x * fb0.x + fa0.y * fb0.y;
        d += fa1.x * fb1.x + fa1.y * fb1.y;
    }
    d += __shfl_xor(d, 1, 64);
    d += __shfl_xor(d, 2, 64);
    d += __shfl_xor(d, 4, 64);
    if (gl == 0) out[p] = d * 0.0625f;
}

// ---------------- launcher ----------------

extern "C" void kernel_launch(void* const* d_in, const int* in_sizes, int n_in,
                              void* d_out, int out_size, void* d_ws, size_t ws_size,
                              hipStream_t stream) {
    const int*   edge_index = (const int*)d_in[0];
    const int*   src  = edge_index;
    const int*   dst  = edge_index + N_EDGES;
    const int*   eli  = (const int*)d_in[1];
    const int*   pa   = eli;
    const int*   pb   = eli + N_PRED;
    const float* emb  = (const float*)d_in[2];
    float*       out  = (float*)d_out;

    char* wsp = (char*)d_ws;
    auto alloc = [&](size_t bytes) -> void* {
        void* p = (void*)wsp;
        wsp += (bytes + 255) & ~(size_t)255;
        return p;
    };
    float*   dinv   = (float*)  alloc((size_t)(N_NODES + 1) * 4);
    int*     deg    = (int*)    alloc((size_t)N_NODES * 4);
    int*     bincur = (int*)    alloc((size_t)NBINS * 4);
    int*     colp   = (int*)    alloc(((size_t)N_NODES * ROWS + 256) * 4);  // 19.2 MB + pad
    __half2* gA     = (__half2*)alloc((size_t)(N_NODES + 1) * 64 * 4);
    __half2* gB     = (__half2*)alloc((size_t)(N_NODES + 1) * 64 * 4);
    __half2* e16    = (__half2*)alloc((size_t)(N_NODES + 1) * 64 * 4);
    // binbuf (8 MB) lifetime-overlaid on gA (first written by agg1, after csr)
    int*     binbuf = (int*)gA;

    const int tb = 256;
    prep_kernel<<<2, tb, 0, stream>>>(bincur, gA, gB, e16, dinv);
    // phase 1: bin+rank via LDS atomics, 153K global reserve atomics | e16 fp16 copy
    bin_or_copy_kernel<<<BIN_NB + CPY_NB, tb, 0, stream>>>(src, dst, emb, bincur, binbuf, e16);
    // phase 2: per-bin CSR finalize + pad16 (zero global atomics), deg + dinv fused
    csr_kernel<<<NBINS, tb, 0, stream>>>(bincur, binbuf, deg, dinv, colp);

    // 3 Horner layers: z_{k+1} = e + A z_k ; wide-gather (4 rows / VMEM instr)
    const int agg_blocks = N_NODES / 4;   // 1 wave per node, 4 waves per block
    agg1_kernel<<<agg_blocks, tb, 0, stream>>>(e16, dinv, deg, colp, gA);          // gA = h2(dv*z1)
    agg_kernel<<<agg_blocks, tb, 0, stream>>>(gA, e16, dinv, deg, colp, gB, 0);    // gB = h2(dv*z2)
    agg_kernel<<<agg_blocks, tb, 0, stream>>>(gB, e16, dinv, deg, colp, gA, 1);    // gA = h2(z3)

    // link-prediction dots on fp16 z3 (exact grid: 15625 * 32 pairs = 500000)
    dot_kernel<<<N_PRED / 32, tb, 0, stream>>>(pa, pb, (const float4*)gA, out);
}

// Round 9
// 265.632 us; speedup vs baseline: 1.1320x; 1.0233x over previous
//
#include <hip/hip_runtime.h>
#include <hip/hip_fp16.h>

#define N_NODES 100000
#define DUMMY   N_NODES
#define DIM     128
#define N_EDGES 1600000
#define N_PRED  500000
#define ROWS    48                                   // slot-table row capacity (max deg ~35)
#define NH2     (N_NODES * 64)                       // 6.4M half2/float2 elements
#define NQ4     (N_NODES * 16)                       // 1.6M float4 rows-of-8-half2
#define CPY_NB  1024                                 // blocks for streaming copy work
#define CPY_STRIDE (CPY_NB * 256)

#define NBINS   391                                  // bin = dst >> 8 (256 nodes/bin)
#define BINCAP  5120                                 // mean 4092, std 64 -> 16 sigma headroom
#define BIN_NB  391                                  // 391*256 threads * 16 edges = 1.6M
#define MAXQ    (BINCAP / 256)                       // 20 edges/thread in csr phase

// ---------------- prep: bincur init + dummy zero-rows ----------------

__global__ __launch_bounds__(256) void prep_kernel(int* __restrict__ bincur,
                                                   __half2* __restrict__ gA,
                                                   __half2* __restrict__ gB,
                                                   __half2* __restrict__ e16,
                                                   float* __restrict__ dinv) {
    int i = blockIdx.x * blockDim.x + threadIdx.x;
    if (i < NBINS) bincur[i] = i * BINCAP;
    if (i < 192) {
        __half2 z = __float22half2_rn(make_float2(0.f, 0.f));
        if (i < 64)       gA[(size_t)DUMMY * 64 + i] = z;
        else if (i < 128) gB[(size_t)DUMMY * 64 + (i - 64)] = z;
        else              e16[(size_t)DUMMY * 64 + (i - 128)] = z;
    }
    if (i == 192) dinv[DUMMY] = 0.0f;
}

// ---------------- phase 1: bin edges (LDS hist + rank, 1 global atomic per block,bin) | e16 copy ----
// packed entry: (local_d << 17) | src,  local_d = dst & 255 (8b), src < 2^17.

__global__ __launch_bounds__(256) void bin_or_copy_kernel(const int* __restrict__ src,
                                                          const int* __restrict__ dst,
                                                          const float* __restrict__ emb,
                                                          int* __restrict__ bincur,
                                                          int* __restrict__ binbuf,
                                                          __half2* __restrict__ e16) {
    int b = blockIdx.x;
    if (b < BIN_NB) {
        __shared__ int hist[NBINS];
        __shared__ int base[NBINS];
        int t = b * 256 + threadIdx.x;
        int e0 = t * 16;
        bool active = (e0 < N_EDGES);   // 1.6M/16 = 100000 threads exactly; no partial tail
        for (int i = threadIdx.x; i < NBINS; i += 256) hist[i] = 0;
        __syncthreads();
        int dd[16], ss[16], lr[16];
        if (active) {
            #pragma unroll
            for (int q = 0; q < 4; ++q) {
                int4 d4 = *(const int4*)&dst[e0 + q * 4];
                int4 s4 = *(const int4*)&src[e0 + q * 4];
                dd[q * 4 + 0] = d4.x; dd[q * 4 + 1] = d4.y; dd[q * 4 + 2] = d4.z; dd[q * 4 + 3] = d4.w;
                ss[q * 4 + 0] = s4.x; ss[q * 4 + 1] = s4.y; ss[q * 4 + 2] = s4.z; ss[q * 4 + 3] = s4.w;
            }
            #pragma unroll
            for (int j = 0; j < 16; ++j) lr[j] = atomicAdd(&hist[dd[j] >> 8], 1);
        }
        __syncthreads();
        // reserve global space: one scattered global atomic per (block, nonempty bin)
        for (int i = threadIdx.x; i < NBINS; i += 256) {
            int h = hist[i];
            base[i] = h ? atomicAdd(&bincur[i], h) : 0;
        }
        __syncthreads();
        if (active) {
            #pragma unroll
            for (int j = 0; j < 16; ++j) {
                int bin = dd[j] >> 8;
                int pos = base[bin] + lr[j];
                if (pos < (bin + 1) * BINCAP)           // capacity guard (never trips)
                    binbuf[pos] = ((dd[j] & 255) << 17) | ss[j];
            }
        }
    } else {
        // ---- streaming emb -> fp16 copy, float4-wide (grid-stride over 1024 blocks) ----
        const float4* em4 = (const float4*)emb;
        float4*       o4  = (float4*)e16;
        int idx = (b - BIN_NB) * 256 + threadIdx.x;
        for (; idx < NQ4; idx += CPY_STRIDE) {
            float4 u = em4[idx * 2];
            float4 v = em4[idx * 2 + 1];
            float4 r;
            __half2* rh = (__half2*)&r;
            rh[0] = __float22half2_rn(make_float2(u.x, u.y));
            rh[1] = __float22half2_rn(make_float2(u.z, u.w));
            rh[2] = __float22half2_rn(make_float2(v.x, v.y));
            rh[3] = __float22half2_rn(make_float2(v.z, v.w));
            o4[idx] = r;
        }
    }
}

// ---------------- phase 2: per-bin CSR finalize + pad16 — zero global atomics ----------------
// rank via LDS atomics on 256 per-node counters; deg/dinv from the LDS histogram;
// rows padded to x16 with DUMMY so agg can do maskless 16-edge batches.

__global__ __launch_bounds__(256) void csr_kernel(const int* __restrict__ bincur,
                                                  const int* __restrict__ binbuf,
                                                  int* __restrict__ deg,
                                                  float* __restrict__ dinv,
                                                  int* __restrict__ colp) {
    int b = blockIdx.x;
    __shared__ int cl[256];
    cl[threadIdx.x] = 0;
    __syncthreads();
    int start = b * BINCAP;
    int cnt = bincur[b] - start;
    if (cnt > BINCAP) cnt = BINCAP;
    int pq[MAXQ], rq[MAXQ];
    #pragma unroll
    for (int q = 0; q < MAXQ; ++q) {
        int i = threadIdx.x + q * 256;
        if (i < cnt) {
            int p = binbuf[start + i];
            pq[q] = p;
            rq[q] = atomicAdd(&cl[p >> 17], 1);
        } else {
            pq[q] = -1;
            rq[q] = ROWS;
        }
    }
    __syncthreads();
    int n = (b << 8) + threadIdx.x;
    if (n < N_NODES) {
        int d = cl[threadIdx.x];
        int dcl = (d > ROWS) ? ROWS : d;
        deg[n] = dcl;
        dinv[n] = (d > 0) ? (float)(1.0 / sqrt((double)d)) : 0.0f;
        int pe = (dcl + 15) & ~15;            // pad row to x16 with DUMMY (maskless agg)
        for (int r = dcl; r < pe; ++r) colp[n * ROWS + r] = DUMMY;
    }
    // scatter real entries (disjoint slots [0, dcl) per node, order-independent)
    #pragma unroll
    for (int q = 0; q < MAXQ; ++q) {
        if (pq[q] >= 0 && rq[q] < ROWS) {
            int ld = pq[q] >> 17;
            colp[(size_t)((b << 8) + ld) * ROWS + rq[q]] = pq[q] & 0x1FFFF;
        }
    }
}

// ---------------- agg: 2 nodes/wave, lane-distributed adjacency, wide gathers ----------------
// ONE VMEM instr loads a node's whole 48-int colp row across lanes; per-(batch,grp)
// edge ids come from __shfl (off the VMEM pipe). grp=lane>>4 picks the edge,
// sub=lane&15 the 16B slice: one dwordx4 gather fetches 4 full 256B rows.

__device__ __forceinline__ void acc8w(float* a, float4 q, float w) {
    const __half2* h = (const __half2*)&q;
    #pragma unroll
    for (int j = 0; j < 4; ++j) {
        float2 f = __half22float2(h[j]);
        a[2 * j]     += w * f.x;
        a[2 * j + 1] += w * f.y;
    }
}

__device__ __forceinline__ void acc8(float* a, float4 q) {
    const __half2* h = (const __half2*)&q;
    #pragma unroll
    for (int j = 0; j < 4; ++j) {
        float2 f = __half22float2(h[j]);
        a[2 * j]     += f.x;
        a[2 * j + 1] += f.y;
    }
}

// layer 1: z = e16[n] + dinv[n] * sum_s dinv[s]*e16[s] ; out = h2(dinv[n]*z)  [mid]
__global__ __launch_bounds__(256) void agg1_kernel(const __half2* __restrict__ e16,
                                                   const float* __restrict__ dinv,
                                                   const int* __restrict__ deg,
                                                   const int* __restrict__ colp,
                                                   __half2* __restrict__ g_out) {
    int wav = (blockIdx.x * 256 + threadIdx.x) >> 6;
    unsigned lane = threadIdx.x & 63;
    int n0 = wav * 2, n1 = n0 + 1;
    if (n0 >= N_NODES) return;              // N even -> n1 always valid
    unsigned grp = lane >> 4, sub = lane & 15;
    unsigned cl = (lane < 47u) ? lane : 47u;
    int ev0 = colp[n0 * ROWS + cl];         // whole adjacency row in one instr
    int ev1 = colp[n1 * ROWS + cl];
    int d0 = deg[n0], d1 = deg[n1];
    int nb0 = (d0 + 15) >> 4, nb1 = (d1 + 15) >> 4;
    const float4* e4 = (const float4*)e16;
    float a0[8] = {0.f, 0.f, 0.f, 0.f, 0.f, 0.f, 0.f, 0.f};
    float a1[8] = {0.f, 0.f, 0.f, 0.f, 0.f, 0.f, 0.f, 0.f};
    int nbm = (nb0 > nb1) ? nb0 : nb1;
    for (int t = 0; t < nbm; ++t) {
        int base = t * 16 + (int)grp;
        if (t < nb0) {
            int ea = __shfl(ev0, base, 64);
            int eb = __shfl(ev0, base + 4, 64);
            int ec = __shfl(ev0, base + 8, 64);
            int ed = __shfl(ev0, base + 12, 64);
            float wa = dinv[ea], wb = dinv[eb], wc = dinv[ec], wd = dinv[ed];
            float4 qa = e4[((unsigned)ea << 4) | sub];
            float4 qb = e4[((unsigned)eb << 4) | sub];
            float4 qc = e4[((unsigned)ec << 4) | sub];
            float4 qd = e4[((unsigned)ed << 4) | sub];
            acc8w(a0, qa, wa); acc8w(a0, qb, wb); acc8w(a0, qc, wc); acc8w(a0, qd, wd);
        }
        if (t < nb1) {
            int ea = __shfl(ev1, base, 64);
            int eb = __shfl(ev1, base + 4, 64);
            int ec = __shfl(ev1, base + 8, 64);
            int ed = __shfl(ev1, base + 12, 64);
            float wa = dinv[ea], wb = dinv[eb], wc = dinv[ec], wd = dinv[ed];
            float4 qa = e4[((unsigned)ea << 4) | sub];
            float4 qb = e4[((unsigned)eb << 4) | sub];
            float4 qc = e4[((unsigned)ec << 4) | sub];
            float4 qd = e4[((unsigned)ed << 4) | sub];
            acc8w(a1, qa, wa); acc8w(a1, qb, wb); acc8w(a1, qc, wc); acc8w(a1, qd, wd);
        }
    }
    #pragma unroll
    for (int k = 0; k < 8; ++k) {
        a0[k] += __shfl_xor(a0[k], 16, 64);
        a0[k] += __shfl_xor(a0[k], 32, 64);
        a1[k] += __shfl_xor(a1[k], 16, 64);
        a1[k] += __shfl_xor(a1[k], 32, 64);
    }
    float dv0 = dinv[n0], dv1 = dinv[n1];
    float4 ev_0 = e4[((unsigned)n0 << 4) | sub];
    float4 ev_1 = e4[((unsigned)n1 << 4) | sub];
    const __half2* eh0 = (const __half2*)&ev_0;
    const __half2* eh1 = (const __half2*)&ev_1;
    float4 r0, r1;
    __half2* rh0 = (__half2*)&r0;
    __half2* rh1 = (__half2*)&r1;
    #pragma unroll
    for (int j = 0; j < 4; ++j) {
        float2 f0 = __half22float2(eh0[j]);
        float2 f1 = __half22float2(eh1[j]);
        rh0[j] = __float22half2_rn(make_float2((f0.x + dv0 * a0[2 * j]) * dv0,
                                               (f0.y + dv0 * a0[2 * j + 1]) * dv0));
        rh1[j] = __float22half2_rn(make_float2((f1.x + dv1 * a1[2 * j]) * dv1,
                                               (f1.y + dv1 * a1[2 * j + 1]) * dv1));
    }
    if (grp == 0) {
        ((float4*)g_out)[((unsigned)n0 << 4) | sub] = r0;
        ((float4*)g_out)[((unsigned)n1 << 4) | sub] = r1;
    }
}

// layers 2/3: z = e16[n] + dinv[n] * sum g_in[col] ; mid: h2(dinv*z) ; last: h2(z)
__global__ __launch_bounds__(256) void agg_kernel(const __half2* __restrict__ g_in,
                                                  const __half2* __restrict__ e16,
                                                  const float* __restrict__ dinv,
                                                  const int* __restrict__ deg,
                                                  const int* __restrict__ colp,
                                                  __half2* __restrict__ g_out,
                                                  int last) {
    int wav = (blockIdx.x * 256 + threadIdx.x) >> 6;
    unsigned lane = threadIdx.x & 63;
    int n0 = wav * 2, n1 = n0 + 1;
    if (n0 >= N_NODES) return;              // N even -> n1 always valid
    unsigned grp = lane >> 4, sub = lane & 15;
    unsigned cl = (lane < 47u) ? lane : 47u;
    int ev0 = colp[n0 * ROWS + cl];
    int ev1 = colp[n1 * ROWS + cl];
    int d0 = deg[n0], d1 = deg[n1];
    int nb0 = (d0 + 15) >> 4, nb1 = (d1 + 15) >> 4;
    const float4* g4 = (const float4*)g_in;
    float a0[8] = {0.f, 0.f, 0.f, 0.f, 0.f, 0.f, 0.f, 0.f};
    float a1[8] = {0.f, 0.f, 0.f, 0.f, 0.f, 0.f, 0.f, 0.f};
    int nbm = (nb0 > nb1) ? nb0 : nb1;
    for (int t = 0; t < nbm; ++t) {
        int base = t * 16 + (int)grp;
        if (t < nb0) {
            int ea = __shfl(ev0, base, 64);
            int eb = __shfl(ev0, base + 4, 64);
            int ec = __shfl(ev0, base + 8, 64);
            int ed = __shfl(ev0, base + 12, 64);
            float4 qa = g4[((unsigned)ea << 4) | sub];
            float4 qb = g4[((unsigned)eb << 4) | sub];
            float4 qc = g4[((unsigned)ec << 4) | sub];
            float4 qd = g4[((unsigned)ed << 4) | sub];
            acc8(a0, qa); acc8(a0, qb); acc8(a0, qc); acc8(a0, qd);
        }
        if (t < nb1) {
            int ea = __shfl(ev1, base, 64);
            int eb = __shfl(ev1, base + 4, 64);
            int ec = __shfl(ev1, base + 8, 64);
            int ed = __shfl(ev1, base + 12, 64);
            float4 qa = g4[((unsigned)ea << 4) | sub];
            float4 qb = g4[((unsigned)eb << 4) | sub];
            float4 qc = g4[((unsigned)ec << 4) | sub];
            float4 qd = g4[((unsigned)ed << 4) | sub];
            acc8(a1, qa); acc8(a1, qb); acc8(a1, qc); acc8(a1, qd);
        }
    }
    #pragma unroll
    for (int k = 0; k < 8; ++k) {
        a0[k] += __shfl_xor(a0[k], 16, 64);
        a0[k] += __shfl_xor(a0[k], 32, 64);
        a1[k] += __shfl_xor(a1[k], 16, 64);
        a1[k] += __shfl_xor(a1[k], 32, 64);
    }
    float dv0 = dinv[n0], dv1 = dinv[n1];
    float4 ev_0 = ((const float4*)e16)[((unsigned)n0 << 4) | sub];
    float4 ev_1 = ((const float4*)e16)[((unsigned)n1 << 4) | sub];
    const __half2* eh0 = (const __half2*)&ev_0;
    const __half2* eh1 = (const __half2*)&ev_1;
    float4 r0, r1;
    __half2* rh0 = (__half2*)&r0;
    __half2* rh1 = (__half2*)&r1;
    #pragma unroll
    for (int j = 0; j < 4; ++j) {
        float2 f0 = __half22float2(eh0[j]);
        float2 f1 = __half22float2(eh1[j]);
        float z0x = f0.x + dv0 * a0[2 * j],     z0y = f0.y + dv0 * a0[2 * j + 1];
        float z1x = f1.x + dv1 * a1[2 * j],     z1y = f1.y + dv1 * a1[2 * j + 1];
        if (!last) { z0x *= dv0; z0y *= dv0; z1x *= dv1; z1y *= dv1; }
        rh0[j] = __float22half2_rn(make_float2(z0x, z0y));
        rh1[j] = __float22half2_rn(make_float2(z1x, z1y));
    }
    if (grp == 0) {
        ((float4*)g_out)[((unsigned)n0 << 4) | sub] = r0;
        ((float4*)g_out)[((unsigned)n1 << 4) | sub] = r1;
    }
}

// 8 pairs/wave, 8 lanes/pair; fp16 z3 rows (256B), 2x float4(=8 half2) per side per lane
__global__ __launch_bounds__(256) void dot_kernel(const int* __restrict__ pa,
                                                  const int* __restrict__ pb,
                                                  const float4* __restrict__ z16,
                                                  float* __restrict__ out) {
    int wid = (blockIdx.x * blockDim.x + threadIdx.x) >> 6;
    int lane = threadIdx.x & 63;
    int slot = lane >> 3;
    int gl = lane & 7;
    int p = wid * 8 + slot;      // exact: 15625 blocks * 32 pairs = 500000
    int a = pa[p], b = pb[p];
    float4 qa0 = z16[(size_t)a * 16 + gl * 2];
    float4 qa1 = z16[(size_t)a * 16 + gl * 2 + 1];
    float4 qb0 = z16[(size_t)b * 16 + gl * 2];
    float4 qb1 = z16[(size_t)b * 16 + gl * 2 + 1];
    const __half2* ha0 = (const __half2*)&qa0;
    const __half2* ha1 = (const __half2*)&qa1;
    const __half2* hb0 = (const __half2*)&qb0;
    const __half2* hb1 = (const __half2*)&qb1;
    float d = 0.f;
    #pragma unroll
    for (int i = 0; i < 4; ++i) {
        float2 fa0 = __half22float2(ha0[i]);
        float2 fb0 = __half22float2(hb0[i]);
        float2 fa1 = __half22float2(ha1[i]);
        float2 fb1 = __half22float2(hb1[i]);
        d += fa0.x * fb0.x + fa0.y * fb0.y;
        d += fa1.x * fb1.x + fa1.y * fb1.y;
    }
    d += __shfl_xor(d, 1, 64);
    d += __shfl_xor(d, 2, 64);
    d += __shfl_xor(d, 4, 64);
    if (gl == 0) out[p] = d * 0.0625f;
}

// ---------------- launcher ----------------

extern "C" void kernel_launch(void* const* d_in, const int* in_sizes, int n_in,
                              void* d_out, int out_size, void* d_ws, size_t ws_size,
                              hipStream_t stream) {
    const int*   edge_index = (const int*)d_in[0];
    const int*   src  = edge_index;
    const int*   dst  = edge_index + N_EDGES;
    const int*   eli  = (const int*)d_in[1];
    const int*   pa   = eli;
    const int*   pb   = eli + N_PRED;
    const float* emb  = (const float*)d_in[2];
    float*       out  = (float*)d_out;

    char* wsp = (char*)d_ws;
    auto alloc = [&](size_t bytes) -> void* {
        void* p = (void*)wsp;
        wsp += (bytes + 255) & ~(size_t)255;
        return p;
    };
    float*   dinv   = (float*)  alloc((size_t)(N_NODES + 1) * 4);
    int*     deg    = (int*)    alloc((size_t)N_NODES * 4);
    int*     bincur = (int*)    alloc((size_t)NBINS * 4);
    int*     colp   = (int*)    alloc(((size_t)N_NODES * ROWS + 256) * 4);  // 19.2 MB + pad
    __half2* gA     = (__half2*)alloc((size_t)(N_NODES + 1) * 64 * 4);
    __half2* gB     = (__half2*)alloc((size_t)(N_NODES + 1) * 64 * 4);
    __half2* e16    = (__half2*)alloc((size_t)(N_NODES + 1) * 64 * 4);
    // binbuf (8 MB) lifetime-overlaid on gA (first written by agg1, after csr)
    int*     binbuf = (int*)gA;

    const int tb = 256;
    prep_kernel<<<2, tb, 0, stream>>>(bincur, gA, gB, e16, dinv);
    // phase 1: bin+rank via LDS atomics, 153K global reserve atomics | e16 fp16 copy
    bin_or_copy_kernel<<<BIN_NB + CPY_NB, tb, 0, stream>>>(src, dst, emb, bincur, binbuf, e16);
    // phase 2: per-bin CSR finalize + pad16 (zero global atomics), deg + dinv fused
    csr_kernel<<<NBINS, tb, 0, stream>>>(bincur, binbuf, deg, dinv, colp);

    // 3 Horner layers: 2 nodes/wave, lane-distributed colp rows, wide gathers
    const int agg_blocks = N_NODES / 8;   // 12500 blocks: 4 waves/block, 2 nodes/wave
    agg1_kernel<<<agg_blocks, tb, 0, stream>>>(e16, dinv, deg, colp, gA);          // gA = h2(dv*z1)
    agg_kernel<<<agg_blocks, tb, 0, stream>>>(gA, e16, dinv, deg, colp, gB, 0);    // gB = h2(dv*z2)
    agg_kernel<<<agg_blocks, tb, 0, stream>>>(gB, e16, dinv, deg, colp, gA, 1);    // gA = h2(z3)

    // link-prediction dots on fp16 z3 (exact grid: 15625 * 32 pairs = 500000)
    dot_kernel<<<N_PRED / 32, tb, 0, stream>>>(pa, pb, (const float4*)gA, out);
}